// Round 8
// baseline (487.012 us; speedup 1.0000x reference)
//
#include <hip/hip_runtime.h>
#include <stdint.h>

#define N_NODES 50000
#define N_REL   3
#define D       128
#define N_EDGES 600000
#define NPAD    50016              // per-relation stride for off/deg arrays
#define BK_SHIFT 10                // bucket covers 1024 nodes
#define NBK     49                 // ceil(50000/1024)
#define BK_CAP  64                 // LDS bin capacity (avg 21 per 1024-edge tile, +9 sigma)
#define BK_TILE 1024               // edges per bucketA block (was 4096: occupancy-starved)
#define REG_CAP 20480              // records per (rel,bucket) region (mean 12288)

typedef unsigned int   uint;
typedef unsigned short ushort_t;
typedef __attribute__((ext_vector_type(8))) short short8v;  // 8 bf16 = 4 VGPRs (MFMA A/B frag)
typedef __attribute__((ext_vector_type(4))) float f32x4;    // MFMA C/D frag

// fp32 -> bf16 round-to-nearest-even
__device__ __forceinline__ ushort_t f2bf(float f)
{
    uint u = __float_as_uint(f);
    u += 0x7FFFu + ((u >> 16) & 1u);
    return (ushort_t)(u >> 16);
}
__device__ __forceinline__ float bf_lo(uint u) { return __uint_as_float(u << 16); }
__device__ __forceinline__ float bf_hi(uint u) { return __uint_as_float(u & 0xFFFF0000u); }

// ---------------------------------------------------------------------------
// zero helper (region cursors are 0xAA-poisoned before every call)
// ---------------------------------------------------------------------------
__global__ __launch_bounds__(256) void zero_cnt(int* __restrict__ p, int n)
{
    const int i = blockIdx.x * 256 + threadIdx.x;
    if (i < n) p[i] = 0;
}

// ---------------------------------------------------------------------------
// cvtW: Wt[r][n][k] = bf16(W[r][k][n]).  147 KB output; L2-resident; ~4 us.
// ---------------------------------------------------------------------------
__global__ __launch_bounds__(256) void cvtW(const float* __restrict__ W,
                                            ushort_t* __restrict__ Wt)
{
    const int idx = blockIdx.x * 256 + threadIdx.x;
    if (idx >= N_REL * D * D) return;
    const int r   = idx >> 14;          // / (128*128)
    const int rem = idx & 16383;
    const int n   = rem >> 7;
    const int k   = rem & 127;
    Wt[idx] = f2bf(W[r * 16384 + k * 128 + n]);
}

// ---------------------------------------------------------------------------
// GEMM (MFMA bf16): wh_all[r] = bf16(x) @ bf16(W[r]) + b[r], fp32 accum.
// Tile 64 rows x 128 cols, whole K=128 in LDS. 4 waves; wave w owns cols
// w*32..w*32+31 (2 N-frags x 4 M-frags x 4 K-steps = 32 MFMA).
// Frag layouts (verified m89/m91 mapping): A/B lane l -> row/col l&15,
// k = 8*(l>>4)+j; C/D lane l reg q -> col l&15, row (l>>4)*4+q.
// B operand = rows of W^T (the ladder's verified B^T pattern).
// +8 ushort row pad: b128 frag reads spread banks (2-way = free).
// ---------------------------------------------------------------------------
__global__ __launch_bounds__(256, 3) void wh_gemm(
    const float* __restrict__ x, const ushort_t* __restrict__ Wt_all,
    const float* __restrict__ b, ushort_t* __restrict__ wh_all)
{
    __shared__ ushort_t xs[64][136];     // 17.4 KB
    __shared__ ushort_t wt[128][136];    // 34.8 KB

    const int r = blockIdx.y;
    const ushort_t* Wt = Wt_all + (size_t)r * D * D;
    const float* br = b + (size_t)r * D;
    ushort_t* wh = wh_all + (size_t)r * N_NODES * D;

    const int tid  = threadIdx.x;
    const int lane = tid & 63;
    const int w    = tid >> 6;
    const int row0 = blockIdx.x * 64;

    // stage x (fp32 -> bf16 inline): 2048 float4, 8/thread
    #pragma unroll
    for (int i = 0; i < 8; ++i) {
        const int idx = i * 256 + tid;
        const int rr  = idx >> 5;
        const int c4  = idx & 31;
        const int gr  = row0 + rr;
        float4 v = make_float4(0.f, 0.f, 0.f, 0.f);
        if (gr < N_NODES) v = *(const float4*)(x + (size_t)gr * D + c4 * 4);
        ushort4 o;
        o.x = f2bf(v.x); o.y = f2bf(v.y); o.z = f2bf(v.z); o.w = f2bf(v.w);
        *(ushort4*)&xs[rr][c4 * 4] = o;
    }
    // stage W^T (already bf16): 2048 x 16B, 8/thread
    #pragma unroll
    for (int i = 0; i < 8; ++i) {
        const int idx = i * 256 + tid;
        const int n   = idx >> 4;
        const int k8  = idx & 15;
        const uint4 v = *(const uint4*)(Wt + n * D + k8 * 8);
        *(uint4*)&wt[n][k8 * 8] = v;
    }
    __syncthreads();

    const int rl = lane & 15;
    const int kg = lane >> 4;

    f32x4 acc[4][2];
    #pragma unroll
    for (int m = 0; m < 4; ++m)
        #pragma unroll
        for (int n = 0; n < 2; ++n) acc[m][n] = (f32x4){0.f, 0.f, 0.f, 0.f};

    #pragma unroll
    for (int ks = 0; ks < 4; ++ks) {
        short8v a[4], bb[2];
        #pragma unroll
        for (int m = 0; m < 4; ++m)
            a[m] = *(const short8v*)&xs[m * 16 + rl][ks * 32 + kg * 8];
        #pragma unroll
        for (int n = 0; n < 2; ++n)
            bb[n] = *(const short8v*)&wt[w * 32 + n * 16 + rl][ks * 32 + kg * 8];
        #pragma unroll
        for (int m = 0; m < 4; ++m)
            #pragma unroll
            for (int n = 0; n < 2; ++n)
                acc[m][n] = __builtin_amdgcn_mfma_f32_16x16x32_bf16(
                    a[m], bb[n], acc[m][n], 0, 0, 0);
    }

    #pragma unroll
    for (int n = 0; n < 2; ++n) {
        const int col = w * 32 + n * 16 + rl;
        const float bias = br[col];
        #pragma unroll
        for (int m = 0; m < 4; ++m)
            #pragma unroll
            for (int q = 0; q < 4; ++q) {
                const int grow = row0 + m * 16 + kg * 4 + q;
                if (grow < N_NODES)
                    wh[(size_t)grow * D + col] = f2bf(acc[m][n][q] + bias);
            }
    }
}

// ---------------------------------------------------------------------------
// bucketA: LDS-staged coarse bucketing by (rel, dst>>10) into fixed regions.
// R7 lesson: 4096-edge tiles -> 441 blocks -> 1.7/CU -> latency-starved.
// Now 1024-edge tiles -> 1758 blocks, 12.8 KB LDS -> ~7 blocks/CU.
// ---------------------------------------------------------------------------
__global__ __launch_bounds__(256) void bucketA(const int* __restrict__ src,
                                               const int* __restrict__ dst,
                                               int* __restrict__ rcur,
                                               uint* __restrict__ bkt)
{
    __shared__ uint bins[NBK][BK_CAP];
    __shared__ int bcnt[NBK];

    const int r   = blockIdx.y;
    const int tid = threadIdx.x;
    const int ebase = blockIdx.x * BK_TILE;

    for (int i = tid; i < NBK; i += 256) bcnt[i] = 0;
    __syncthreads();

    const int* srcr = src + (size_t)r * N_EDGES;
    const int* dstr = dst + (size_t)r * N_EDGES;

    #pragma unroll
    for (int t = 0; t < BK_TILE / 256; ++t) {
        const int e = ebase + t * 256 + tid;
        if (e < N_EDGES) {
            const uint d = (uint)dstr[e];
            const uint s = (uint)srcr[e];
            const int cb = (int)(d >> BK_SHIFT);
            const uint rec = ((d & 1023u) << 16) | s;
            const int lp = atomicAdd(&bcnt[cb], 1);
            if (lp < BK_CAP) {
                bins[cb][lp] = rec;
            } else {  // ~never: correct direct write via region cursor
                const int p = atomicAdd(&rcur[r * NBK + cb], 1);
                bkt[(size_t)(r * NBK + cb) * REG_CAP + p] = rec;
            }
        }
    }
    __syncthreads();

    const int lane = tid & 63, wid = tid >> 6;
    for (int bin = wid; bin < NBK; bin += 4) {
        const int n = min(bcnt[bin], BK_CAP);
        if (n == 0) continue;
        int basep = 0;
        if (lane == 0) basep = atomicAdd(&rcur[r * NBK + bin], n);
        basep = __shfl(basep, 0, 64);
        uint* dstp = bkt + (size_t)(r * NBK + bin) * REG_CAP + basep;
        for (int i = lane; i < n; i += 64) dstp[i] = bins[bin][i];
    }
}

// ---------------------------------------------------------------------------
// placeB: per (rel,bucket) block builds the bucket's CSR in LDS:
// histogram -> scan -> off/deg -> place into srt's region (L2-hot window).
// ---------------------------------------------------------------------------
__global__ __launch_bounds__(1024) void placeB(const uint* __restrict__ bkt,
                                               const int* __restrict__ rcur,
                                               int* __restrict__ off,
                                               int* __restrict__ deg,
                                               int* __restrict__ srt)
{
    __shared__ int hcnt[1024];
    __shared__ int pcur[1024];
    __shared__ int wtot[16], wexc[16];

    const int bx        = blockIdx.x;
    const int r         = blockIdx.y;
    const int region    = r * NBK + bx;
    const size_t rbase  = (size_t)region * REG_CAP;
    const int nrec      = rcur[region];
    const int node_base = bx << BK_SHIFT;
    const int tid       = threadIdx.x;
    const int lane      = tid & 63;
    const int wid       = tid >> 6;

    hcnt[tid] = 0;
    __syncthreads();

    for (int j = tid; j < nrec; j += 1024)
        atomicAdd(&hcnt[bkt[rbase + j] >> 16], 1);
    __syncthreads();

    const int orig = hcnt[tid];
    int v = orig;
    #pragma unroll
    for (int s = 1; s < 64; s <<= 1) {
        const int t = __shfl_up(v, s, 64);
        if (lane >= s) v += t;
    }
    if (lane == 63) wtot[wid] = v;
    __syncthreads();
    if (tid == 0) {
        int run = 0;
        #pragma unroll
        for (int w = 0; w < 16; ++w) { const int t = wtot[w]; wexc[w] = run; run += t; }
    }
    __syncthreads();
    const int excl = wexc[wid] + (v - orig);

    const int node = node_base + tid;
    if (node < N_NODES) {
        off[r * NPAD + node] = (int)rbase + excl;
        deg[r * NPAD + node] = orig;
    }
    pcur[tid] = excl;
    __syncthreads();

    for (int j = tid; j < nrec; j += 1024) {
        const uint rec = bkt[rbase + j];
        const int d = (int)(rec >> 16);
        const int s = (int)(rec & 0xFFFFu);
        const int p = atomicAdd(&pcur[d], 1);
        srt[rbase + p] = s;
    }
}

// ---------------------------------------------------------------------------
// Aggregate (bf16 gather): 16 lanes per dst node, each owns 8 columns.
// fp32 register accumulation; single store per node; uses off/deg.
// ---------------------------------------------------------------------------
__global__ __launch_bounds__(256) void aggregate(const ushort_t* __restrict__ wh_all,
                                                 const int* __restrict__ off,
                                                 const int* __restrict__ deg,
                                                 const int* __restrict__ srt,
                                                 float* __restrict__ out)
{
    const int g    = (blockIdx.x * 256 + threadIdx.x) >> 4;
    const int lane = threadIdx.x & 15;
    if (g >= N_NODES) return;

    float acc[8];
    #pragma unroll
    for (int j = 0; j < 8; ++j) acc[j] = 0.0f;

    for (int r = 0; r < N_REL; ++r) {
        const ushort_t* wh = wh_all + (size_t)r * N_NODES * D;
        const int e0 = off[r * NPAD + g];
        const int e1 = e0 + deg[r * NPAD + g];
        int i = e0;
        for (; i + 2 <= e1; i += 2) {
            const int s0 = srt[i];
            const int s1 = srt[i + 1];
            const uint4 v0 = *(const uint4*)(wh + (size_t)s0 * D + lane * 8);
            const uint4 v1 = *(const uint4*)(wh + (size_t)s1 * D + lane * 8);
            acc[0] += bf_lo(v0.x); acc[1] += bf_hi(v0.x);
            acc[2] += bf_lo(v0.y); acc[3] += bf_hi(v0.y);
            acc[4] += bf_lo(v0.z); acc[5] += bf_hi(v0.z);
            acc[6] += bf_lo(v0.w); acc[7] += bf_hi(v0.w);
            acc[0] += bf_lo(v1.x); acc[1] += bf_hi(v1.x);
            acc[2] += bf_lo(v1.y); acc[3] += bf_hi(v1.y);
            acc[4] += bf_lo(v1.z); acc[5] += bf_hi(v1.z);
            acc[6] += bf_lo(v1.w); acc[7] += bf_hi(v1.w);
        }
        if (i < e1) {
            const int s0 = srt[i];
            const uint4 v0 = *(const uint4*)(wh + (size_t)s0 * D + lane * 8);
            acc[0] += bf_lo(v0.x); acc[1] += bf_hi(v0.x);
            acc[2] += bf_lo(v0.y); acc[3] += bf_hi(v0.y);
            acc[4] += bf_lo(v0.z); acc[5] += bf_hi(v0.z);
            acc[6] += bf_lo(v0.w); acc[7] += bf_hi(v0.w);
        }
    }

    float* o = out + (size_t)g * D + lane * 8;
    *(float4*)(o + 0) = make_float4(acc[0], acc[1], acc[2], acc[3]);
    *(float4*)(o + 4) = make_float4(acc[4], acc[5], acc[6], acc[7]);
}

extern "C" void kernel_launch(void* const* d_in, const int* in_sizes, int n_in,
                              void* d_out, int out_size, void* d_ws, size_t ws_size,
                              hipStream_t stream)
{
    const float* x   = (const float*)d_in[0];
    const float* W   = (const float*)d_in[1];
    const float* b   = (const float*)d_in[2];
    const int*   src = (const int*)d_in[3];
    const int*   dst = (const int*)d_in[4];
    float* out = (float*)d_out;

    const int gemm_gx = (N_NODES + 63) / 64;          // 782
    const int agg_gx  = (N_NODES * 16 + 255) / 256;   // 3125
    const int bkA_gx  = (N_EDGES + BK_TILE - 1) / BK_TILE;  // 586
    const int L       = N_REL * NPAD;                 // 150048
    const int NREG    = N_REL * NBK;                  // 147

    // Workspace layout (~64 MB; ws proven >= 93 MB in earlier rounds):
    char* base   = (char*)d_ws;
    ushort_t* wh = (ushort_t*)base;                               // 38.4 MB
    int* off     = (int*)(base + (size_t)N_REL * N_NODES * D * 2);// L ints
    int* deg     = off + L;                                       // L ints
    int* rcur    = deg + L;                                       // 256 ints
    uint* bkt    = (uint*)(rcur + 256);                           // 12 MB
    int*  srt    = (int*)(bkt + (size_t)NREG * REG_CAP);          // 12 MB
    ushort_t* Wt = (ushort_t*)(srt + (size_t)NREG * REG_CAP);     // 96 KB (16B-aligned)

    cvtW<<<(N_REL * D * D + 255) / 256, 256, 0, stream>>>(W, Wt);
    wh_gemm<<<dim3(gemm_gx, N_REL), 256, 0, stream>>>(x, Wt, b, wh);
    zero_cnt<<<1, 256, 0, stream>>>(rcur, NREG);
    bucketA<<<dim3(bkA_gx, N_REL), 256, 0, stream>>>(src, dst, rcur, bkt);
    placeB<<<dim3(NBK, N_REL), 1024, 0, stream>>>(bkt, rcur, off, deg, srt);
    aggregate<<<agg_gx, 256, 0, stream>>>(wh, off, deg, srt, out);
}

// Round 11
// 218.005 us; speedup vs baseline: 2.2339x; 2.2339x over previous
//
#include <hip/hip_runtime.h>
#include <stdint.h>

#define N_NODES 50000
#define N_REL   3
#define D       128
#define N_EDGES 600000
#define NPAD    50016              // per-relation stride for off/deg arrays
#define BK_SHIFT 10                // bucket covers 1024 nodes
#define NBK     49                 // ceil(50000/1024)
#define NCHUNK  512                // edge chunks per relation
#define CH_EDGES 1172              // 512*1172 = 600064 >= N_EDGES
#define CH_CAP  64                 // slots per (chunk,bin); mean 23.9, ~+8 sigma
#define OVF_CAP 8192               // per-rel overflow list (expected use: ~0)
#define REG_CAP 20480              // srt records per (rel,bucket) region

typedef unsigned int   uint;
typedef unsigned short ushort_t;
typedef __attribute__((ext_vector_type(8))) short short8v;  // 8 bf16 (MFMA A/B frag)
typedef __attribute__((ext_vector_type(4))) float f32x4;    // MFMA C/D frag

// fp32 -> bf16 round-to-nearest-even
__device__ __forceinline__ ushort_t f2bf(float f)
{
    uint u = __float_as_uint(f);
    u += 0x7FFFu + ((u >> 16) & 1u);
    return (ushort_t)(u >> 16);
}
__device__ __forceinline__ float bf_lo(uint u) { return __uint_as_float(u << 16); }
__device__ __forceinline__ float bf_hi(uint u) { return __uint_as_float(u & 0xFFFF0000u); }

// ---------------------------------------------------------------------------
__global__ __launch_bounds__(256) void zero_cnt(int* __restrict__ p, int n)
{
    const int i = blockIdx.x * 256 + threadIdx.x;
    if (i < n) p[i] = 0;
}

// ---------------------------------------------------------------------------
// cvtW: Wt[r][n][k] = bf16(W[r][k][n])
// ---------------------------------------------------------------------------
__global__ __launch_bounds__(256) void cvtW(const float* __restrict__ W,
                                            ushort_t* __restrict__ Wt)
{
    const int idx = blockIdx.x * 256 + threadIdx.x;
    if (idx >= N_REL * D * D) return;
    const int r   = idx >> 14;
    const int rem = idx & 16383;
    const int n   = rem >> 7;
    const int k   = rem & 127;
    Wt[idx] = f2bf(W[r * 16384 + k * 128 + n]);
}

// ---------------------------------------------------------------------------
// GEMM (MFMA bf16, unchanged from R8 -- absmax proved insensitive):
// 64x128 tile, whole K in LDS, 4 waves x 32 MFMA. Verified m89/m91 layouts.
// ---------------------------------------------------------------------------
__global__ __launch_bounds__(256, 3) void wh_gemm(
    const float* __restrict__ x, const ushort_t* __restrict__ Wt_all,
    const float* __restrict__ b, ushort_t* __restrict__ wh_all)
{
    __shared__ ushort_t xs[64][136];
    __shared__ ushort_t wt[128][136];

    const int r = blockIdx.y;
    const ushort_t* Wt = Wt_all + (size_t)r * D * D;
    const float* br = b + (size_t)r * D;
    ushort_t* wh = wh_all + (size_t)r * N_NODES * D;

    const int tid  = threadIdx.x;
    const int lane = tid & 63;
    const int w    = tid >> 6;
    const int row0 = blockIdx.x * 64;

    #pragma unroll
    for (int i = 0; i < 8; ++i) {
        const int idx = i * 256 + tid;
        const int rr  = idx >> 5;
        const int c4  = idx & 31;
        const int gr  = row0 + rr;
        float4 v = make_float4(0.f, 0.f, 0.f, 0.f);
        if (gr < N_NODES) v = *(const float4*)(x + (size_t)gr * D + c4 * 4);
        ushort4 o;
        o.x = f2bf(v.x); o.y = f2bf(v.y); o.z = f2bf(v.z); o.w = f2bf(v.w);
        *(ushort4*)&xs[rr][c4 * 4] = o;
    }
    #pragma unroll
    for (int i = 0; i < 8; ++i) {
        const int idx = i * 256 + tid;
        const int n   = idx >> 4;
        const int k8  = idx & 15;
        const uint4 v = *(const uint4*)(Wt + n * D + k8 * 8);
        *(uint4*)&wt[n][k8 * 8] = v;
    }
    __syncthreads();

    const int rl = lane & 15;
    const int kg = lane >> 4;

    f32x4 acc[4][2];
    #pragma unroll
    for (int m = 0; m < 4; ++m)
        #pragma unroll
        for (int n = 0; n < 2; ++n) acc[m][n] = (f32x4){0.f, 0.f, 0.f, 0.f};

    #pragma unroll
    for (int ks = 0; ks < 4; ++ks) {
        short8v a[4], bb[2];
        #pragma unroll
        for (int m = 0; m < 4; ++m)
            a[m] = *(const short8v*)&xs[m * 16 + rl][ks * 32 + kg * 8];
        #pragma unroll
        for (int n = 0; n < 2; ++n)
            bb[n] = *(const short8v*)&wt[w * 32 + n * 16 + rl][ks * 32 + kg * 8];
        #pragma unroll
        for (int m = 0; m < 4; ++m)
            #pragma unroll
            for (int n = 0; n < 2; ++n)
                acc[m][n] = __builtin_amdgcn_mfma_f32_16x16x32_bf16(
                    a[m], bb[n], acc[m][n], 0, 0, 0);
    }

    #pragma unroll
    for (int n = 0; n < 2; ++n) {
        const int col = w * 32 + n * 16 + rl;
        const float bias = br[col];
        #pragma unroll
        for (int m = 0; m < 4; ++m)
            #pragma unroll
            for (int q = 0; q < 4; ++q) {
                const int grow = row0 + m * 16 + kg * 4 + q;
                if (grow < N_NODES)
                    wh[(size_t)grow * D + col] = f2bf(acc[m][n][q] + bias);
            }
    }
}

// ---------------------------------------------------------------------------
// bucketA2: deterministic bucketing -- ZERO global atomics on the hot path.
// Block = (chunk, rel): bins its CH_EDGES edges in LDS by dst>>10, then
// flushes bin b to the PRIVATE region bkt[rel][b][chunk][0..n) and writes
// ccnt[rel][b][chunk] = n (unconditionally -- an empty bin must still clear
// its poisoned count). R8 lesson: shared global cursors serialize cross-XCD
// (~299us); private slots need no coordination. Record = (dst<<16)|src.
// Overflow (>CH_CAP) -> tiny per-rel list via atomic (expected ~0 events).
// ---------------------------------------------------------------------------
__global__ __launch_bounds__(256) void bucketA2(const int* __restrict__ src,
                                                const int* __restrict__ dst,
                                                uint* __restrict__ bkt,
                                                int* __restrict__ ccnt,
                                                uint* __restrict__ ovf,
                                                int* __restrict__ ovf_cnt)
{
    __shared__ uint bins[NBK][CH_CAP];
    __shared__ int bcnt[NBK];

    const int r   = blockIdx.y;
    const int ch  = blockIdx.x;
    const int tid = threadIdx.x;

    for (int i = tid; i < NBK; i += 256) bcnt[i] = 0;
    __syncthreads();

    const int* srcr = src + (size_t)r * N_EDGES;
    const int* dstr = dst + (size_t)r * N_EDGES;
    const int e0 = ch * CH_EDGES;
    const int e1 = min(e0 + CH_EDGES, N_EDGES);

    for (int e = e0 + tid; e < e1; e += 256) {
        const uint d = (uint)dstr[e];
        const uint s = (uint)srcr[e];
        const int cb = (int)(d >> BK_SHIFT);
        const uint rec = (d << 16) | s;
        const int lp = atomicAdd(&bcnt[cb], 1);
        if (lp < CH_CAP) {
            bins[cb][lp] = rec;
        } else {  // ~never; correctness net
            const int p = atomicAdd(&ovf_cnt[r], 1);
            ovf[(size_t)r * OVF_CAP + p] = rec;
        }
    }
    __syncthreads();

    const int lane = tid & 63, wid = tid >> 6;
    for (int bin = wid; bin < NBK; bin += 4) {
        const int n = min(bcnt[bin], CH_CAP);
        if (lane == 0) ccnt[(r * NBK + bin) * NCHUNK + ch] = n;  // ALWAYS write
        if (n == 0) continue;
        uint* dp = bkt + ((size_t)(r * NBK + bin) * NCHUNK + ch) * CH_CAP;
        for (int i = lane; i < n; i += 64) dp[i] = bins[bin][i];
    }
}

// ---------------------------------------------------------------------------
// placeB2: per (rel,bucket) block. Stages the bucket's 512 chunk-counts to
// LDS, iterates the capacity grid (slot valid iff slot < count[chunk]):
// pass 1 = LDS histogram over 1024 nodes, scan -> off/deg; pass 2 = place
// into srt's region via LDS cursors. Overflow list scanned & filtered.
// ---------------------------------------------------------------------------
__global__ __launch_bounds__(1024) void placeB2(const uint* __restrict__ bkt,
                                                const int* __restrict__ ccnt,
                                                const uint* __restrict__ ovf,
                                                const int* __restrict__ ovf_cnt,
                                                int* __restrict__ off,
                                                int* __restrict__ deg,
                                                int* __restrict__ srt)
{
    __shared__ int hcnt[1024];
    __shared__ int pcur[1024];
    __shared__ int ccl[NCHUNK];
    __shared__ int wtot[16], wexc[16];

    const int bx        = blockIdx.x;
    const int r         = blockIdx.y;
    const int region    = r * NBK + bx;
    const size_t rbase  = (size_t)region * REG_CAP;
    const int node_base = bx << BK_SHIFT;
    const int tid       = threadIdx.x;
    const int lane      = tid & 63;
    const int wid       = tid >> 6;

    hcnt[tid] = 0;
    for (int i = tid; i < NCHUNK; i += 1024) ccl[i] = ccnt[region * NCHUNK + i];
    __syncthreads();

    const uint* bb  = bkt + (size_t)region * (NCHUNK * CH_CAP);
    const int   nov = ovf_cnt[r];
    const uint* ovr = ovf + (size_t)r * OVF_CAP;

    // pass 1: histogram (slot index: sidx = ch*64 + sl; CH_CAP == 64)
    for (int sidx = tid; sidx < NCHUNK * CH_CAP; sidx += 1024) {
        if ((sidx & 63) < ccl[sidx >> 6])
            atomicAdd(&hcnt[(bb[sidx] >> 16) & 1023], 1);
    }
    for (int j = tid; j < nov; j += 1024) {
        const uint d = ovr[j] >> 16;
        if ((int)(d >> BK_SHIFT) == bx) atomicAdd(&hcnt[d & 1023], 1);
    }
    __syncthreads();

    // exclusive scan of 1024 counts
    const int orig = hcnt[tid];
    int v = orig;
    #pragma unroll
    for (int s = 1; s < 64; s <<= 1) {
        const int t = __shfl_up(v, s, 64);
        if (lane >= s) v += t;
    }
    if (lane == 63) wtot[wid] = v;
    __syncthreads();
    if (tid == 0) {
        int run = 0;
        #pragma unroll
        for (int w = 0; w < 16; ++w) { const int t = wtot[w]; wexc[w] = run; run += t; }
    }
    __syncthreads();
    const int excl = wexc[wid] + (v - orig);

    const int node = node_base + tid;
    if (node < N_NODES) {
        off[r * NPAD + node] = (int)rbase + excl;
        deg[r * NPAD + node] = orig;
    }
    pcur[tid] = excl;
    __syncthreads();

    // pass 2: place
    for (int sidx = tid; sidx < NCHUNK * CH_CAP; sidx += 1024) {
        if ((sidx & 63) < ccl[sidx >> 6]) {
            const uint rec = bb[sidx];
            const int p = atomicAdd(&pcur[(rec >> 16) & 1023], 1);
            srt[rbase + p] = (int)(rec & 0xFFFFu);
        }
    }
    for (int j = tid; j < nov; j += 1024) {
        const uint rec = ovr[j];
        const uint d = rec >> 16;
        if ((int)(d >> BK_SHIFT) == bx) {
            const int p = atomicAdd(&pcur[d & 1023], 1);
            srt[rbase + p] = (int)(rec & 0xFFFFu);
        }
    }
}

// ---------------------------------------------------------------------------
// Aggregate (bf16 gather, unchanged): 16 lanes per dst node, fp32 accum,
// single store per node; uses off/deg (srt has inter-region gaps).
// ---------------------------------------------------------------------------
__global__ __launch_bounds__(256) void aggregate(const ushort_t* __restrict__ wh_all,
                                                 const int* __restrict__ off,
                                                 const int* __restrict__ deg,
                                                 const int* __restrict__ srt,
                                                 float* __restrict__ out)
{
    const int g    = (blockIdx.x * 256 + threadIdx.x) >> 4;
    const int lane = threadIdx.x & 15;
    if (g >= N_NODES) return;

    float acc[8];
    #pragma unroll
    for (int j = 0; j < 8; ++j) acc[j] = 0.0f;

    for (int r = 0; r < N_REL; ++r) {
        const ushort_t* wh = wh_all + (size_t)r * N_NODES * D;
        const int e0 = off[r * NPAD + g];
        const int e1 = e0 + deg[r * NPAD + g];
        int i = e0;
        for (; i + 2 <= e1; i += 2) {
            const int s0 = srt[i];
            const int s1 = srt[i + 1];
            const uint4 v0 = *(const uint4*)(wh + (size_t)s0 * D + lane * 8);
            const uint4 v1 = *(const uint4*)(wh + (size_t)s1 * D + lane * 8);
            acc[0] += bf_lo(v0.x); acc[1] += bf_hi(v0.x);
            acc[2] += bf_lo(v0.y); acc[3] += bf_hi(v0.y);
            acc[4] += bf_lo(v0.z); acc[5] += bf_hi(v0.z);
            acc[6] += bf_lo(v0.w); acc[7] += bf_hi(v0.w);
            acc[0] += bf_lo(v1.x); acc[1] += bf_hi(v1.x);
            acc[2] += bf_lo(v1.y); acc[3] += bf_hi(v1.y);
            acc[4] += bf_lo(v1.z); acc[5] += bf_hi(v1.z);
            acc[6] += bf_lo(v1.w); acc[7] += bf_hi(v1.w);
        }
        if (i < e1) {
            const int s0 = srt[i];
            const uint4 v0 = *(const uint4*)(wh + (size_t)s0 * D + lane * 8);
            acc[0] += bf_lo(v0.x); acc[1] += bf_hi(v0.x);
            acc[2] += bf_lo(v0.y); acc[3] += bf_hi(v0.y);
            acc[4] += bf_lo(v0.z); acc[5] += bf_hi(v0.z);
            acc[6] += bf_lo(v0.w); acc[7] += bf_hi(v0.w);
        }
    }

    float* o = out + (size_t)g * D + lane * 8;
    *(float4*)(o + 0) = make_float4(acc[0], acc[1], acc[2], acc[3]);
    *(float4*)(o + 4) = make_float4(acc[4], acc[5], acc[6], acc[7]);
}

extern "C" void kernel_launch(void* const* d_in, const int* in_sizes, int n_in,
                              void* d_out, int out_size, void* d_ws, size_t ws_size,
                              hipStream_t stream)
{
    const float* x   = (const float*)d_in[0];
    const float* W   = (const float*)d_in[1];
    const float* b   = (const float*)d_in[2];
    const int*   src = (const int*)d_in[3];
    const int*   dst = (const int*)d_in[4];
    float* out = (float*)d_out;

    const int gemm_gx = (N_NODES + 63) / 64;          // 782
    const int agg_gx  = (N_NODES * 16 + 255) / 256;   // 3125
    const int L       = N_REL * NPAD;                 // 150048
    const int NREG    = N_REL * NBK;                  // 147

    // Workspace layout (~71.3 MB; ws proven >= 93 MB in earlier rounds):
    char* base    = (char*)d_ws;
    ushort_t* wh  = (ushort_t*)base;                               // 38.4 MB
    int* off      = (int*)(base + (size_t)N_REL * N_NODES * D * 2);// L ints
    int* deg      = off + L;                                       // L ints
    int* ovf_cnt  = deg + L;                                       // 16 ints
    uint* ovf     = (uint*)(ovf_cnt + 16);                         // 3*8192 uints
    int* ccnt     = (int*)(ovf + (size_t)N_REL * OVF_CAP);         // 75264 ints
    uint* bkt     = (uint*)(ccnt + NREG * NCHUNK);                 // 19.3 MB
    int*  srt     = (int*)(bkt + (size_t)NREG * NCHUNK * CH_CAP);  // 12 MB
    ushort_t* Wt  = (ushort_t*)(srt + (size_t)NREG * REG_CAP);     // 96 KB

    cvtW<<<(N_REL * D * D + 255) / 256, 256, 0, stream>>>(W, Wt);
    wh_gemm<<<dim3(gemm_gx, N_REL), 256, 0, stream>>>(x, Wt, b, wh);
    zero_cnt<<<1, 256, 0, stream>>>(ovf_cnt, 16);
    bucketA2<<<dim3(NCHUNK, N_REL), 256, 0, stream>>>(src, dst, bkt, ccnt, ovf, ovf_cnt);
    placeB2<<<dim3(NBK, N_REL), 1024, 0, stream>>>(bkt, ccnt, ovf, ovf_cnt, off, deg, srt);
    aggregate<<<agg_gx, 256, 0, stream>>>(wh, off, deg, srt, out);
}